// Round 4
// baseline (2283.636 us; speedup 1.0000x reference)
//
#include <hip/hip_runtime.h>

// Problem constants: BATCH=16, N=128, D=128, N_STEPS=5, EPS=1e-10
#define EPSF 1e-10f

// ============================ K1: Cayley bases ============================
// M = I + A, A = L - L^T. Symmetric part of M is I (SPD) => unpivoted
// Gauss-Jordan is stable (all pivots >= 1). U = 2*M^{-1} - I.
// LDS layout: float4 (i, j4) stored at f4 index i*32 + (j4 ^ (i & 31)).
// Thread map in the k-loop: within a wave, lane -> row = w*16 + (lane&15),
// chunk h = lane>>4. Each 8-lane beat then hits 8 distinct rows, whose
// XOR-swizzled f4 addresses span all 8 4-bank groups -> conflict-free b128.
#define SWZ4(i, j4) ((i) * 32 + ((j4) ^ ((i) & 31)))
#define SWZF(i, j) (SWZ4((i), (j) >> 2) * 4 + ((j) & 3))

__global__ __launch_bounds__(512, 2) void k_cayley(const float* __restrict__ L,
                                                   float* __restrict__ bases) {
  extern __shared__ float4 M4[];  // 4096 float4 = 64 KB
  float* Mf = (float*)M4;
  const int n = blockIdx.x, t = threadIdx.x;
  const float* Ln = L + n * 16384;
  // load linear -> swizzled (coalesced global reads)
  for (int f = t; f < 4096; f += 512) {
    int i = f >> 5, j4 = f & 31;
    M4[SWZ4(i, j4)] = ((const float4*)Ln)[f];
  }
  __syncthreads();
  // antisymmetrize in place + unit diagonal (pair (i<j) owned by one thread)
  for (int f = t; f < 16384; f += 512) {
    int i = f >> 7, j = f & 127;
    if (i < j) {
      int a = SWZF(i, j), b = SWZF(j, i);
      float va = Mf[a], vb = Mf[b];
      Mf[a] = va - vb;
      Mf[b] = vb - va;
    } else if (i == j) {
      Mf[SWZF(i, i)] = 1.0f;
    }
  }
  __syncthreads();
  const int lane = t & 63, wva = t >> 6;
  const int i = wva * 16 + (lane & 15);  // row owned by this thread
  const int h = lane >> 4;               // which 8-float4 chunk of the row
  for (int k = 0; k < 128; ++k) {
    // ---- phase A: all reads (pre-barrier; nothing written since last barrier)
    float pivinv = 1.0f / Mf[SWZF(k, k)];   // broadcast
    float m = Mf[SWZF(i, k)];               // column read, conflict-spread
    float4 rk[8], a[8];
    #pragma unroll
    for (int u = 0; u < 8; ++u) rk[u] = M4[SWZ4(k, h * 8 + u)];  // bcast/beat
    #pragma unroll
    for (int u = 0; u < 8; ++u) a[u] = M4[SWZ4(i, h * 8 + u)];
    __syncthreads();
    // ---- phase B: pure FMA + writes (in-place GJ step, col-k patch folded)
    float coef = m * pivinv;
    if (i == k) {
      #pragma unroll
      for (int u = 0; u < 8; ++u) {
        int jj = h * 8 + u;
        float4 v = rk[u];
        v.x *= pivinv; v.y *= pivinv; v.z *= pivinv; v.w *= pivinv;
        if (jj == (k >> 2)) ((float*)&v)[k & 3] = pivinv;
        M4[SWZ4(k, jj)] = v;
      }
    } else {
      #pragma unroll
      for (int u = 0; u < 8; ++u) {
        int jj = h * 8 + u;
        float4 av = a[u];
        float4 r = rk[u];
        av.x -= coef * r.x; av.y -= coef * r.y;
        av.z -= coef * r.z; av.w -= coef * r.w;
        if (jj == (k >> 2)) ((float*)&av)[k & 3] = -coef;
        M4[SWZ4(i, jj)] = av;
      }
    }
    __syncthreads();
  }
  // write U = 2*Minv - I (coalesced global writes)
  for (int f = t; f < 16384; f += 512) {
    int ii = f >> 7, j = f & 127;
    float v = Mf[SWZF(ii, j)];
    bases[n * 16384 + f] = 2.0f * v - ((ii == j) ? 1.0f : 0.0f);
  }
}

// ============================ K2a: Gram of flattened bases ============================
__global__ __launch_bounds__(256) void k_gram(const float* __restrict__ bases,
                                              float* __restrict__ G) {
  const int i = blockIdx.x, t = threadIdx.x;
  __shared__ float redb[4];
  float4 ai[16];
  const float4* Bi = (const float4*)(bases + i * 16384);
  #pragma unroll
  for (int u = 0; u < 16; ++u) ai[u] = Bi[t + 256 * u];
  for (int j = 0; j < 128; ++j) {
    const float4* Bj = (const float4*)(bases + j * 16384);
    float acc = 0.f;
    #pragma unroll
    for (int u = 0; u < 16; ++u) {
      float4 b = Bj[t + 256 * u];
      acc += ai[u].x * b.x + ai[u].y * b.y + ai[u].z * b.z + ai[u].w * b.w;
    }
    for (int s = 32; s > 0; s >>= 1) acc += __shfl_down(acc, s);
    if ((t & 63) == 0) redb[t >> 6] = acc;
    __syncthreads();
    if (t == 0) G[i * 128 + j] = redb[0] + redb[1] + redb[2] + redb[3];
    __syncthreads();
  }
}

// ============================ K2b: tension + softmax + mask ============================
__global__ __launch_bounds__(128) void k_wsoft(const float* __restrict__ G,
                                               const float* __restrict__ temp_p,
                                               float* __restrict__ w,
                                               float* __restrict__ tension_out) {
  const int i = blockIdx.x, t = threadIdx.x;  // t = j
  __shared__ float rr[2], r2[2];
  float temp = fmaxf(fabsf(*temp_p), 0.01f);
  float gii = G[i * 128 + i], gjj = G[t * 128 + t], gij = G[i * 128 + t];
  float ten = sqrtf(fmaxf(gii + gjj - 2.0f * gij, 0.0f) + 1e-8f);
  tension_out[i * 128 + t] = ten;
  float logit = -ten / temp;
  float m = logit;
  for (int s = 32; s > 0; s >>= 1) m = fmaxf(m, __shfl_xor(m, s));
  if ((t & 63) == 0) rr[t >> 6] = m;
  __syncthreads();
  float mx = fmaxf(rr[0], rr[1]);
  float ex = expf(logit - mx);
  float ssum = ex;
  for (int s = 32; s > 0; s >>= 1) ssum += __shfl_xor(ssum, s);
  if ((t & 63) == 0) r2[t >> 6] = ssum;
  __syncthreads();
  float tot = r2[0] + r2[1];
  float wv = ex / tot;
  if (t == i) wv = 0.0f;
  w[i * 128 + t] = wv;
}

// ============================ K3: measurements + initial norms ============================
__global__ __launch_bounds__(128) void k_meas(const float* __restrict__ x,
                                              const float* __restrict__ bases,
                                              float* __restrict__ meas_out,
                                              float* __restrict__ state0,
                                              float* __restrict__ norms0) {
  const int n = blockIdx.x, t = threadIdx.x;  // t = k
  __shared__ float xs[2048];
  __shared__ float red[2];
  for (int f = t; f < 2048; f += 128) xs[f] = x[f];
  __syncthreads();
  float acc[16];
  #pragma unroll
  for (int b = 0; b < 16; ++b) acc[b] = 0.f;
  for (int d = 0; d < 128; ++d) {
    float u = bases[n * 16384 + d * 128 + t];  // coalesced over t
    #pragma unroll
    for (int b = 0; b < 16; ++b) acc[b] += xs[b * 128 + d] * u;
  }
  for (int b = 0; b < 16; ++b) {
    meas_out[(b * 128 + n) * 128 + t] = acc[b];
    state0[(b * 128 + n) * 128 + t] = acc[b];
  }
  for (int b = 0; b < 16; ++b) {
    float v = acc[b] * acc[b];
    for (int s = 32; s > 0; s >>= 1) v += __shfl_down(v, s);
    if ((t & 63) == 0) red[t >> 6] = v;
    __syncthreads();
    if (t == 0) norms0[b * 128 + n] = sqrtf(red[0] + red[1]);
    __syncthreads();
  }
}

// ============================ K4: one interaction step ============================
__global__ __launch_bounds__(128) void k_step(const float* __restrict__ src,
                                              float* __restrict__ dst,
                                              const float* __restrict__ w,
                                              const float* __restrict__ norms_in,
                                              float* __restrict__ norms_out,
                                              const float* __restrict__ tgt_p,
                                              const float* __restrict__ step_p) {
  const int b = blockIdx.x >> 7, n = blockIdx.x & 127, t = threadIdx.x;
  __shared__ float sn[128];
  __shared__ float chunk[32][129];
  __shared__ float red[2][32][2];
  __shared__ float cbuf[32];
  __shared__ float red2[2];
  const float target = *tgt_p;
  const float step = fminf(fmaxf(fabsf(*step_p), 0.001f), 0.5f);
  const float* srcb = src + b * 16384;
  float x_d = srcb[n * 128 + t];
  sn[t] = x_d;
  float norm_n = norms_in[b * 128 + n];
  float f_d = 0.0f;
  __syncthreads();
  for (int c0 = 0; c0 < 128; c0 += 32) {
    for (int f = t; f < 4096; f += 128) {
      int row = f >> 7, col = f & 127;
      chunk[row][col] = srcb[(c0 + row) * 128 + col];
    }
    __syncthreads();
    int m = t & 31, q = t >> 5;
    float dp = 0.f, sp = 0.f;
    const float* cr = &chunk[m][0];
    #pragma unroll
    for (int i2 = 0; i2 < 32; ++i2) {
      int dd = q * 32 + i2;
      float smv = cr[dd];
      float snd = sn[dd];
      dp += smv * snd;
      float df = snd - smv;
      sp += df * df;
    }
    dp += __shfl_xor(dp, 32);
    sp += __shfl_xor(sp, 32);
    int wave = t >> 6;
    if ((t & 63) < 32) { red[wave][m][0] = dp; red[wave][m][1] = sp; }
    __syncthreads();
    if (t < 32) {
      float dot = red[0][t][0] + red[1][t][0];
      float sq  = red[0][t][1] + red[1][t][1];
      int mm = c0 + t;
      float norm_m = norms_in[b * 128 + mm];
      float wnm = w[n * 128 + mm];
      float cs = dot / ((norm_n + EPSF) * (norm_m + EPSF));
      float fm = (cs - target) * wnm;
      cbuf[t] = fm / (sqrtf(fmaxf(sq, 0.0f)) + EPSF);
    }
    __syncthreads();
    #pragma unroll
    for (int mi = 0; mi < 32; ++mi) f_d += cbuf[mi] * (x_d - chunk[mi][t]);
    __syncthreads();
  }
  float nv = x_d + step * f_d;
  dst[(b * 128 + n) * 128 + t] = nv;
  float v = nv * nv;
  for (int s = 32; s > 0; s >>= 1) v += __shfl_down(v, s);
  if ((t & 63) == 0) red2[t >> 6] = v;
  __syncthreads();
  if (t == 0) norms_out[b * 128 + n] = sqrtf(red2[0] + red2[1]);
}

// ============================ K5: expressions ============================
__global__ __launch_bounds__(128) void k_expr(const float* __restrict__ eq,
                                              const float* __restrict__ bases,
                                              float* __restrict__ expr_out) {
  const int n = blockIdx.x, t = threadIdx.x;  // t = k
  __shared__ __align__(16) float es[16][128];
  for (int f = t; f < 2048; f += 128)
    es[f >> 7][f & 127] = eq[((f >> 7) * 128 + n) * 128 + (f & 127)];
  __syncthreads();
  float acc[16];
  #pragma unroll
  for (int b = 0; b < 16; ++b) acc[b] = 0.f;
  const float4* U = (const float4*)(bases + n * 16384 + t * 128);
  for (int d4 = 0; d4 < 32; ++d4) {
    float4 u = U[d4];
    #pragma unroll
    for (int b = 0; b < 16; ++b) {
      float4 e4 = ((const float4*)&es[b][0])[d4];
      acc[b] += u.x * e4.x + u.y * e4.y + u.z * e4.z + u.w * e4.w;
    }
  }
  for (int b = 0; b < 16; ++b) expr_out[(b * 128 + n) * 128 + t] = acc[b];
}

// ============================ K5b: output_avg ============================
__global__ __launch_bounds__(128) void k_avg(const float* __restrict__ expr,
                                             float* __restrict__ avg) {
  const int b = blockIdx.x, t = threadIdx.x;
  float s = 0.f;
  for (int n = 0; n < 128; ++n) s += expr[(b * 128 + n) * 128 + t];
  avg[b * 128 + t] = s * (1.0f / 128.0f);
}

// ============================ K6: rho ============================
__global__ __launch_bounds__(256) void k_rho(const float* __restrict__ eq,
                                             const float* __restrict__ norms,
                                             float* __restrict__ rho) {
  const int b = blockIdx.x >> 3, dt = blockIdx.x & 7;
  const int t = threadIdx.x;
  __shared__ float ch[32][129];
  int e = t & 127, dl = t >> 7;
  float acc[8];
  #pragma unroll
  for (int o = 0; o < 8; ++o) acc[o] = 0.f;
  for (int c0 = 0; c0 < 128; c0 += 32) {
    for (int f = t; f < 4096; f += 256) {
      int row = f >> 7, col = f & 127;
      int nn = c0 + row;
      float inv = 1.0f / (norms[b * 128 + nn] + EPSF);
      ch[row][col] = eq[(b * 128 + nn) * 128 + col] * inv;
    }
    __syncthreads();
    for (int nn = 0; nn < 32; ++nn) {
      float me = ch[nn][e];
      #pragma unroll
      for (int o = 0; o < 8; ++o) {
        int d = dt * 16 + dl + o * 2;
        acc[o] += ch[nn][d] * me;
      }
    }
    __syncthreads();
  }
  for (int o = 0; o < 8; ++o) {
    int d = dt * 16 + dl + o * 2;
    rho[(b * 128 + d) * 128 + e] = acc[o] * (1.0f / 128.0f);
  }
}

// ============================ K7: Householder tridiagonalization ============================
// 128 threads (2 waves), float4-swizzled LDS (all b128 traffic), 3 barriers
// per step. v stored dense with zeros below k+1; q = p - K*v folded into the
// rank-2 update (no qv pass). Column read after update is same-thread only,
// so the loop carries no extra barrier. vv ping-pongs by step parity; x0 is
// broadcast via a dedicated slot to avoid the vv[k+1] read/write race.
#define TSW(i, j4) ((i) * 32 + ((j4) ^ ((i) & 31)))
#define AEL(i, j) (Af[TSW((i), (j) >> 2) * 4 + ((j) & 3)])

__global__ __launch_bounds__(128) void k_tridiag(const float* __restrict__ rho,
                                                 float* __restrict__ dvec_g,
                                                 float* __restrict__ evec_g) {
  extern __shared__ float sm[];
  float4* A4  = (float4*)sm;        // 4096 float4 = 64 KB
  float*  Af  = sm;
  float* vvb  = sm + 16384;         // 2 x 128 ping-pong
  float* pv   = vvb + 256;          // 128
  float* dv   = pv + 128;           // 128
  float* evr  = dv + 128;           // 128
  float* redS = evr + 128;          // 2
  float* redK = redS + 2;           // 2
  float* redX = redK + 2;           // 1 (+pad)
  const int bb = blockIdx.x, t = threadIdx.x;
  const int wv = t >> 6;
  const float* R = rho + bb * 16384;
  for (int f = t; f < 4096; f += 128)
    A4[TSW(f >> 5, f & 31)] = ((const float4*)R)[f];
  __syncthreads();
  for (int k = 0; k < 126; ++k) {
    float* vvC = vvb + ((k & 1) << 7);
    // ---- P1: column k -> vv (zeros at t<=k), sigma^2 partials, x0 broadcast
    float c = AEL(t, k);
    vvC[t] = (t > k) ? c : 0.0f;
    if (t == k) dv[k] = c;
    if (t == k + 1) redX[0] = c;
    float s2 = (t > k) ? c * c : 0.0f;
    for (int s = 32; s > 0; s >>= 1) s2 += __shfl_down(s2, s);
    if ((t & 63) == 0) redS[wv] = s2;
    __syncthreads();  // B1
    // ---- P2: alpha/beta redundant per-thread; patch vv[k+1]
    float sig2 = redS[0] + redS[1];
    float x0 = redX[0];
    bool skip = (sig2 < 1e-30f);
    float sig = sqrtf(sig2);
    float alpha = (x0 >= 0.0f) ? -sig : sig;
    float beta = skip ? 0.0f : 1.0f / (sig2 - alpha * x0);
    float w0 = x0 - alpha;
    if (t == k + 1) {
      evr[k] = skip ? 0.0f : alpha;
      if (!skip) vvC[t] = w0;
    }
    __syncthreads();  // B2
    if (!skip) {  // uniform branch
      const int j4min = (k + 1) >> 2;
      // ---- P3: matvec p = beta * A v (row per thread), K partials
      float pp = 0.0f;
      if (t > k) {
        const float4* v4 = (const float4*)vvC;
        for (int j4 = j4min; j4 < 32; ++j4) {
          float4 a = A4[TSW(t, j4)];
          float4 v = v4[j4];
          pp += a.x * v.x + a.y * v.y + a.z * v.z + a.w * v.w;
        }
      }
      float p = beta * pp;
      pv[t] = p;                 // zero for t<=k
      float kp = vvC[t] * p;     // zero for t<=k
      for (int s = 32; s > 0; s >>= 1) kp += __shfl_down(kp, s);
      if ((t & 63) == 0) redK[wv] = kp;
      __syncthreads();  // B3
      // ---- P4: rank-2 update A -= v q^T + q v^T, q = p - K v on the fly
      float K = (redK[0] + redK[1]) * beta * 0.5f;
      if (t > k) {
        float vi = vvC[t];
        float qi = pv[t] - K * vi;
        const float4* v4 = (const float4*)vvC;
        const float4* p4 = (const float4*)pv;
        for (int j4 = j4min; j4 < 32; ++j4) {
          float4 a = A4[TSW(t, j4)];
          float4 v = v4[j4], pq = p4[j4];
          float qx = pq.x - K * v.x, qy = pq.y - K * v.y;
          float qz = pq.z - K * v.z, qw = pq.w - K * v.w;
          a.x -= vi * qx + qi * v.x;
          a.y -= vi * qy + qi * v.y;
          a.z -= vi * qz + qi * v.z;
          a.w -= vi * qw + qi * v.w;
          A4[TSW(t, j4)] = a;
        }
      }
    }
  }
  __syncthreads();
  if (t == 0) {
    dv[126]  = AEL(126, 126);
    evr[126] = AEL(127, 126);
    dv[127]  = AEL(127, 127);
    evr[127] = 0.0f;
  }
  __syncthreads();
  dvec_g[bb * 128 + t] = dv[t];
  evec_g[bb * 128 + t] = evr[t];
}

// ============================ K8: bisection eigenvalues + normalize ============================
__global__ __launch_bounds__(128) void k_bisect(const float* __restrict__ dvec_g,
                                                const float* __restrict__ evec_g,
                                                float* __restrict__ dist_out) {
  const int bb = blockIdx.x, t = threadIdx.x;
  __shared__ float ds[128], e2s[128], eabs[128];
  __shared__ float rr[2];
  ds[t] = dvec_g[bb * 128 + t];
  float e = evec_g[bb * 128 + t];
  e2s[t] = e * e;
  eabs[t] = fabsf(e);
  __syncthreads();
  float lo = 1e30f, hi = -1e30f;
  for (int ii = 0; ii < 128; ++ii) {
    float r = (ii > 0 ? eabs[ii - 1] : 0.0f) + (ii < 127 ? eabs[ii] : 0.0f);
    lo = fminf(lo, ds[ii] - r);
    hi = fmaxf(hi, ds[ii] + r);
  }
  for (int it = 0; it < 40; ++it) {
    float mid = 0.5f * (lo + hi);
    int cnt = 0;
    float q = ds[0] - mid;
    if (q < 0.0f) cnt++;
    for (int ii = 1; ii < 128; ++ii) {
      float denom = q;
      if (fabsf(denom) < 1e-25f) denom = (denom < 0.0f) ? -1e-25f : 1e-25f;
      q = (ds[ii] - mid) - __fdividef(e2s[ii - 1], denom);
      if (q < 0.0f) cnt++;
    }
    if (cnt <= t) lo = mid; else hi = mid;
  }
  float lam = 0.5f * (lo + hi);
  float evc = fmaxf(lam, 1e-12f);
  float ssum = evc;
  for (int s = 32; s > 0; s >>= 1) ssum += __shfl_xor(ssum, s);
  if ((t & 63) == 0) rr[t >> 6] = ssum;
  __syncthreads();
  float tot = rr[0] + rr[1];
  dist_out[bb * 128 + t] = evc / tot;
}

// ============================ launch ============================
extern "C" void kernel_launch(void* const* d_in, const int* in_sizes, int n_in,
                              void* d_out, int out_size, void* d_ws, size_t ws_size,
                              hipStream_t stream) {
  const float* x      = (const float*)d_in[0];
  const float* L      = (const float*)d_in[1];
  const float* temp_p = (const float*)d_in[2];
  const float* tgt_p  = (const float*)d_in[3];
  const float* step_p = (const float*)d_in[4];
  float* out = (float*)d_out;
  float* ws  = (float*)d_ws;

  float* bases = ws;                    // 2097152
  float* G     = bases + 2097152;       // 16384
  float* w     = G + 16384;             // 16384
  float* s0    = w + 16384;             // 262144
  float* s1    = s0 + 262144;           // 262144
  float* n0    = s1 + 262144;           // 2048
  float* n1    = n0 + 2048;             // 2048
  float* dv    = n1 + 2048;             // 2048
  float* ev    = dv + 2048;             // 2048

  float* o_avg  = out;                  // 2048
  float* o_dist = out + 2048;           // 2048
  float* o_rho  = out + 4096;           // 262144
  float* o_meas = out + 266240;         // 262144
  float* o_eq   = out + 528384;         // 262144
  float* o_expr = out + 790528;         // 262144
  float* o_ten  = out + 1052672;        // 16384

  hipFuncSetAttribute((const void*)k_cayley,
                      hipFuncAttributeMaxDynamicSharedMemorySize, 65536);
  hipFuncSetAttribute((const void*)k_tridiag,
                      hipFuncAttributeMaxDynamicSharedMemorySize, 68160);

  k_cayley<<<128, 512, 65536, stream>>>(L, bases);
  k_gram<<<128, 256, 0, stream>>>(bases, G);
  k_wsoft<<<128, 128, 0, stream>>>(G, temp_p, w, o_ten);
  k_meas<<<128, 128, 0, stream>>>(x, bases, o_meas, s0, n0);
  k_step<<<2048, 128, 0, stream>>>(s0, s1, w, n0, n1, tgt_p, step_p);
  k_step<<<2048, 128, 0, stream>>>(s1, s0, w, n1, n0, tgt_p, step_p);
  k_step<<<2048, 128, 0, stream>>>(s0, s1, w, n0, n1, tgt_p, step_p);
  k_step<<<2048, 128, 0, stream>>>(s1, s0, w, n1, n0, tgt_p, step_p);
  k_step<<<2048, 128, 0, stream>>>(s0, o_eq, w, n0, n1, tgt_p, step_p);
  k_expr<<<128, 128, 0, stream>>>(o_eq, bases, o_expr);
  k_avg<<<16, 128, 0, stream>>>(o_expr, o_avg);
  k_rho<<<128, 256, 0, stream>>>(o_eq, n1, o_rho);
  k_tridiag<<<16, 128, 68160, stream>>>(o_rho, dv, ev);
  k_bisect<<<16, 128, 0, stream>>>(dv, ev, o_dist);
}

// Round 5
// 1847.989 us; speedup vs baseline: 1.2357x; 1.2357x over previous
//
#include <hip/hip_runtime.h>

// Problem constants: BATCH=16, N=128, D=128, N_STEPS=5, EPS=1e-10
#define EPSF 1e-10f

// ============================ K1: Cayley bases ============================
// M = I + A, A = L - L^T. Symmetric part of M is I (SPD) => unpivoted
// Gauss-Jordan is stable (all pivots >= 1). U = 2*M^{-1} - I.
// LDS layout: float4 (i, j4) stored at f4 index i*32 + (j4 ^ (i & 31)).
// Lane map: row i = wave*16 + (lane&15), chunk h = lane>>4 (4 threads/row,
// 8 float4 each). Each 8-lane beat hits 8 distinct rows -> swizzled
// addresses span all 8 bank groups -> conflict-free b128.
// SPILL FIX (r4): preload ONLY rk[8] (row k) across the barrier. The a[]
// row-slice is self-owned (no other thread writes it), so it is streamed
// read-FMA-write inside phase B with ~2 float4 live. Keeps VGPR < 64.
#define SWZ4(i, j4) ((i) * 32 + ((j4) ^ ((i) & 31)))
#define SWZF(i, j) (SWZ4((i), (j) >> 2) * 4 + ((j) & 3))

__global__ __launch_bounds__(512, 2) void k_cayley(const float* __restrict__ L,
                                                   float* __restrict__ bases) {
  extern __shared__ float4 M4[];  // 4096 float4 = 64 KB
  float* Mf = (float*)M4;
  const int n = blockIdx.x, t = threadIdx.x;
  const float* Ln = L + n * 16384;
  // load linear -> swizzled (coalesced global reads)
  for (int f = t; f < 4096; f += 512) {
    int i = f >> 5, j4 = f & 31;
    M4[SWZ4(i, j4)] = ((const float4*)Ln)[f];
  }
  __syncthreads();
  // antisymmetrize in place + unit diagonal (pair (i<j) owned by one thread)
  for (int f = t; f < 16384; f += 512) {
    int i = f >> 7, j = f & 127;
    if (i < j) {
      int a = SWZF(i, j), b = SWZF(j, i);
      float va = Mf[a], vb = Mf[b];
      Mf[a] = va - vb;
      Mf[b] = vb - va;
    } else if (i == j) {
      Mf[SWZF(i, i)] = 1.0f;
    }
  }
  __syncthreads();
  const int lane = t & 63, wva = t >> 6;
  const int i = wva * 16 + (lane & 15);  // row owned by this thread
  const int h = lane >> 4;               // which 8-float4 chunk of the row
  for (int k = 0; k < 128; ++k) {
    // ---- phase A: cross-thread reads only (pivot, multiplier, row k)
    float pivinv = 1.0f / Mf[SWZF(k, k)];   // broadcast
    float m = Mf[SWZF(i, k)];               // column read, conflict-spread
    float4 rk[8];
    #pragma unroll
    for (int u = 0; u < 8; ++u) rk[u] = M4[SWZ4(k, h * 8 + u)];  // bcast/beat
    __syncthreads();
    // ---- phase B: stream own row slice (self-owned: no cross-thread race)
    float coef = m * pivinv;
    if (i == k) {
      #pragma unroll
      for (int u = 0; u < 8; ++u) {
        int jj = h * 8 + u;
        float4 v = rk[u];
        v.x *= pivinv; v.y *= pivinv; v.z *= pivinv; v.w *= pivinv;
        if (jj == (k >> 2)) ((float*)&v)[k & 3] = pivinv;
        M4[SWZ4(k, jj)] = v;
      }
    } else {
      #pragma unroll
      for (int u = 0; u < 8; ++u) {
        int jj = h * 8 + u;
        float4 av = M4[SWZ4(i, jj)];  // read here, not preloaded (no spill)
        float4 r = rk[u];
        av.x -= coef * r.x; av.y -= coef * r.y;
        av.z -= coef * r.z; av.w -= coef * r.w;
        if (jj == (k >> 2)) ((float*)&av)[k & 3] = -coef;
        M4[SWZ4(i, jj)] = av;
      }
    }
    __syncthreads();
  }
  // write U = 2*Minv - I (coalesced global writes)
  for (int f = t; f < 16384; f += 512) {
    int ii = f >> 7, j = f & 127;
    float v = Mf[SWZF(ii, j)];
    bases[n * 16384 + f] = 2.0f * v - ((ii == j) ? 1.0f : 0.0f);
  }
}

// ============================ K2a: Gram of flattened bases ============================
__global__ __launch_bounds__(256) void k_gram(const float* __restrict__ bases,
                                              float* __restrict__ G) {
  const int i = blockIdx.x, t = threadIdx.x;
  __shared__ float redb[4];
  float4 ai[16];
  const float4* Bi = (const float4*)(bases + i * 16384);
  #pragma unroll
  for (int u = 0; u < 16; ++u) ai[u] = Bi[t + 256 * u];
  for (int j = 0; j < 128; ++j) {
    const float4* Bj = (const float4*)(bases + j * 16384);
    float acc = 0.f;
    #pragma unroll
    for (int u = 0; u < 16; ++u) {
      float4 b = Bj[t + 256 * u];
      acc += ai[u].x * b.x + ai[u].y * b.y + ai[u].z * b.z + ai[u].w * b.w;
    }
    for (int s = 32; s > 0; s >>= 1) acc += __shfl_down(acc, s);
    if ((t & 63) == 0) redb[t >> 6] = acc;
    __syncthreads();
    if (t == 0) G[i * 128 + j] = redb[0] + redb[1] + redb[2] + redb[3];
    __syncthreads();
  }
}

// ============================ K2b: tension + softmax + mask ============================
__global__ __launch_bounds__(128) void k_wsoft(const float* __restrict__ G,
                                               const float* __restrict__ temp_p,
                                               float* __restrict__ w,
                                               float* __restrict__ tension_out) {
  const int i = blockIdx.x, t = threadIdx.x;  // t = j
  __shared__ float rr[2], r2[2];
  float temp = fmaxf(fabsf(*temp_p), 0.01f);
  float gii = G[i * 128 + i], gjj = G[t * 128 + t], gij = G[i * 128 + t];
  float ten = sqrtf(fmaxf(gii + gjj - 2.0f * gij, 0.0f) + 1e-8f);
  tension_out[i * 128 + t] = ten;
  float logit = -ten / temp;
  float m = logit;
  for (int s = 32; s > 0; s >>= 1) m = fmaxf(m, __shfl_xor(m, s));
  if ((t & 63) == 0) rr[t >> 6] = m;
  __syncthreads();
  float mx = fmaxf(rr[0], rr[1]);
  float ex = expf(logit - mx);
  float ssum = ex;
  for (int s = 32; s > 0; s >>= 1) ssum += __shfl_xor(ssum, s);
  if ((t & 63) == 0) r2[t >> 6] = ssum;
  __syncthreads();
  float tot = r2[0] + r2[1];
  float wv = ex / tot;
  if (t == i) wv = 0.0f;
  w[i * 128 + t] = wv;
}

// ============================ K3: measurements + initial norms ============================
__global__ __launch_bounds__(128) void k_meas(const float* __restrict__ x,
                                              const float* __restrict__ bases,
                                              float* __restrict__ meas_out,
                                              float* __restrict__ state0,
                                              float* __restrict__ norms0) {
  const int n = blockIdx.x, t = threadIdx.x;  // t = k
  __shared__ float xs[2048];
  __shared__ float red[2];
  for (int f = t; f < 2048; f += 128) xs[f] = x[f];
  __syncthreads();
  float acc[16];
  #pragma unroll
  for (int b = 0; b < 16; ++b) acc[b] = 0.f;
  for (int d = 0; d < 128; ++d) {
    float u = bases[n * 16384 + d * 128 + t];  // coalesced over t
    #pragma unroll
    for (int b = 0; b < 16; ++b) acc[b] += xs[b * 128 + d] * u;
  }
  for (int b = 0; b < 16; ++b) {
    meas_out[(b * 128 + n) * 128 + t] = acc[b];
    state0[(b * 128 + n) * 128 + t] = acc[b];
  }
  for (int b = 0; b < 16; ++b) {
    float v = acc[b] * acc[b];
    for (int s = 32; s > 0; s >>= 1) v += __shfl_down(v, s);
    if ((t & 63) == 0) red[t >> 6] = v;
    __syncthreads();
    if (t == 0) norms0[b * 128 + n] = sqrtf(red[0] + red[1]);
    __syncthreads();
  }
}

// ============================ K4: one interaction step ============================
__global__ __launch_bounds__(128) void k_step(const float* __restrict__ src,
                                              float* __restrict__ dst,
                                              const float* __restrict__ w,
                                              const float* __restrict__ norms_in,
                                              float* __restrict__ norms_out,
                                              const float* __restrict__ tgt_p,
                                              const float* __restrict__ step_p) {
  const int b = blockIdx.x >> 7, n = blockIdx.x & 127, t = threadIdx.x;
  __shared__ float sn[128];
  __shared__ float chunk[32][129];
  __shared__ float red[2][32][2];
  __shared__ float cbuf[32];
  __shared__ float red2[2];
  const float target = *tgt_p;
  const float step = fminf(fmaxf(fabsf(*step_p), 0.001f), 0.5f);
  const float* srcb = src + b * 16384;
  float x_d = srcb[n * 128 + t];
  sn[t] = x_d;
  float norm_n = norms_in[b * 128 + n];
  float f_d = 0.0f;
  __syncthreads();
  for (int c0 = 0; c0 < 128; c0 += 32) {
    for (int f = t; f < 4096; f += 128) {
      int row = f >> 7, col = f & 127;
      chunk[row][col] = srcb[(c0 + row) * 128 + col];
    }
    __syncthreads();
    int m = t & 31, q = t >> 5;
    float dp = 0.f, sp = 0.f;
    const float* cr = &chunk[m][0];
    #pragma unroll
    for (int i2 = 0; i2 < 32; ++i2) {
      int dd = q * 32 + i2;
      float smv = cr[dd];
      float snd = sn[dd];
      dp += smv * snd;
      float df = snd - smv;
      sp += df * df;
    }
    dp += __shfl_xor(dp, 32);
    sp += __shfl_xor(sp, 32);
    int wave = t >> 6;
    if ((t & 63) < 32) { red[wave][m][0] = dp; red[wave][m][1] = sp; }
    __syncthreads();
    if (t < 32) {
      float dot = red[0][t][0] + red[1][t][0];
      float sq  = red[0][t][1] + red[1][t][1];
      int mm = c0 + t;
      float norm_m = norms_in[b * 128 + mm];
      float wnm = w[n * 128 + mm];
      float cs = dot / ((norm_n + EPSF) * (norm_m + EPSF));
      float fm = (cs - target) * wnm;
      cbuf[t] = fm / (sqrtf(fmaxf(sq, 0.0f)) + EPSF);
    }
    __syncthreads();
    #pragma unroll
    for (int mi = 0; mi < 32; ++mi) f_d += cbuf[mi] * (x_d - chunk[mi][t]);
    __syncthreads();
  }
  float nv = x_d + step * f_d;
  dst[(b * 128 + n) * 128 + t] = nv;
  float v = nv * nv;
  for (int s = 32; s > 0; s >>= 1) v += __shfl_down(v, s);
  if ((t & 63) == 0) red2[t >> 6] = v;
  __syncthreads();
  if (t == 0) norms_out[b * 128 + n] = sqrtf(red2[0] + red2[1]);
}

// ============================ K5: expressions ============================
__global__ __launch_bounds__(128) void k_expr(const float* __restrict__ eq,
                                              const float* __restrict__ bases,
                                              float* __restrict__ expr_out) {
  const int n = blockIdx.x, t = threadIdx.x;  // t = k
  __shared__ __align__(16) float es[16][128];
  for (int f = t; f < 2048; f += 128)
    es[f >> 7][f & 127] = eq[((f >> 7) * 128 + n) * 128 + (f & 127)];
  __syncthreads();
  float acc[16];
  #pragma unroll
  for (int b = 0; b < 16; ++b) acc[b] = 0.f;
  const float4* U = (const float4*)(bases + n * 16384 + t * 128);
  for (int d4 = 0; d4 < 32; ++d4) {
    float4 u = U[d4];
    #pragma unroll
    for (int b = 0; b < 16; ++b) {
      float4 e4 = ((const float4*)&es[b][0])[d4];
      acc[b] += u.x * e4.x + u.y * e4.y + u.z * e4.z + u.w * e4.w;
    }
  }
  for (int b = 0; b < 16; ++b) expr_out[(b * 128 + n) * 128 + t] = acc[b];
}

// ============================ K5b: output_avg ============================
__global__ __launch_bounds__(128) void k_avg(const float* __restrict__ expr,
                                             float* __restrict__ avg) {
  const int b = blockIdx.x, t = threadIdx.x;
  float s = 0.f;
  for (int n = 0; n < 128; ++n) s += expr[(b * 128 + n) * 128 + t];
  avg[b * 128 + t] = s * (1.0f / 128.0f);
}

// ============================ K6: rho ============================
__global__ __launch_bounds__(256) void k_rho(const float* __restrict__ eq,
                                             const float* __restrict__ norms,
                                             float* __restrict__ rho) {
  const int b = blockIdx.x >> 3, dt = blockIdx.x & 7;
  const int t = threadIdx.x;
  __shared__ float ch[32][129];
  int e = t & 127, dl = t >> 7;
  float acc[8];
  #pragma unroll
  for (int o = 0; o < 8; ++o) acc[o] = 0.f;
  for (int c0 = 0; c0 < 128; c0 += 32) {
    for (int f = t; f < 4096; f += 256) {
      int row = f >> 7, col = f & 127;
      int nn = c0 + row;
      float inv = 1.0f / (norms[b * 128 + nn] + EPSF);
      ch[row][col] = eq[(b * 128 + nn) * 128 + col] * inv;
    }
    __syncthreads();
    for (int nn = 0; nn < 32; ++nn) {
      float me = ch[nn][e];
      #pragma unroll
      for (int o = 0; o < 8; ++o) {
        int d = dt * 16 + dl + o * 2;
        acc[o] += ch[nn][d] * me;
      }
    }
    __syncthreads();
  }
  for (int o = 0; o < 8; ++o) {
    int d = dt * 16 + dl + o * 2;
    rho[(b * 128 + d) * 128 + e] = acc[o] * (1.0f / 128.0f);
  }
}

// ============================ K7: Householder tridiagonalization ============================
// 128 threads (2 waves), float4-swizzled LDS (all b128 traffic), 3 barriers
// per step. v stored dense with zeros below k+1; q = p - K*v folded into the
// rank-2 update (no qv pass). Column read after update is same-thread only,
// so the loop carries no extra barrier. vv ping-pongs by step parity; x0 is
// broadcast via a dedicated slot to avoid the vv[k+1] read/write race.
#define TSW(i, j4) ((i) * 32 + ((j4) ^ ((i) & 31)))
#define AEL(i, j) (Af[TSW((i), (j) >> 2) * 4 + ((j) & 3)])

__global__ __launch_bounds__(128) void k_tridiag(const float* __restrict__ rho,
                                                 float* __restrict__ dvec_g,
                                                 float* __restrict__ evec_g) {
  extern __shared__ float sm[];
  float4* A4  = (float4*)sm;        // 4096 float4 = 64 KB
  float*  Af  = sm;
  float* vvb  = sm + 16384;         // 2 x 128 ping-pong
  float* pv   = vvb + 256;          // 128
  float* dv   = pv + 128;           // 128
  float* evr  = dv + 128;           // 128
  float* redS = evr + 128;          // 2
  float* redK = redS + 2;           // 2
  float* redX = redK + 2;           // 1 (+pad)
  const int bb = blockIdx.x, t = threadIdx.x;
  const int wv = t >> 6;
  const float* R = rho + bb * 16384;
  for (int f = t; f < 4096; f += 128)
    A4[TSW(f >> 5, f & 31)] = ((const float4*)R)[f];
  __syncthreads();
  for (int k = 0; k < 126; ++k) {
    float* vvC = vvb + ((k & 1) << 7);
    // ---- P1: column k -> vv (zeros at t<=k), sigma^2 partials, x0 broadcast
    float c = AEL(t, k);
    vvC[t] = (t > k) ? c : 0.0f;
    if (t == k) dv[k] = c;
    if (t == k + 1) redX[0] = c;
    float s2 = (t > k) ? c * c : 0.0f;
    for (int s = 32; s > 0; s >>= 1) s2 += __shfl_down(s2, s);
    if ((t & 63) == 0) redS[wv] = s2;
    __syncthreads();  // B1
    // ---- P2: alpha/beta redundant per-thread; patch vv[k+1]
    float sig2 = redS[0] + redS[1];
    float x0 = redX[0];
    bool skip = (sig2 < 1e-30f);
    float sig = sqrtf(sig2);
    float alpha = (x0 >= 0.0f) ? -sig : sig;
    float beta = skip ? 0.0f : 1.0f / (sig2 - alpha * x0);
    float w0 = x0 - alpha;
    if (t == k + 1) {
      evr[k] = skip ? 0.0f : alpha;
      if (!skip) vvC[t] = w0;
    }
    __syncthreads();  // B2
    if (!skip) {  // uniform branch
      const int j4min = (k + 1) >> 2;
      // ---- P3: matvec p = beta * A v (row per thread), K partials
      float pp = 0.0f;
      if (t > k) {
        const float4* v4 = (const float4*)vvC;
        for (int j4 = j4min; j4 < 32; ++j4) {
          float4 a = A4[TSW(t, j4)];
          float4 v = v4[j4];
          pp += a.x * v.x + a.y * v.y + a.z * v.z + a.w * v.w;
        }
      }
      float p = beta * pp;
      pv[t] = p;                 // zero for t<=k
      float kp = vvC[t] * p;     // zero for t<=k
      for (int s = 32; s > 0; s >>= 1) kp += __shfl_down(kp, s);
      if ((t & 63) == 0) redK[wv] = kp;
      __syncthreads();  // B3
      // ---- P4: rank-2 update A -= v q^T + q v^T, q = p - K v on the fly
      float K = (redK[0] + redK[1]) * beta * 0.5f;
      if (t > k) {
        float vi = vvC[t];
        float qi = pv[t] - K * vi;
        const float4* v4 = (const float4*)vvC;
        const float4* p4 = (const float4*)pv;
        for (int j4 = j4min; j4 < 32; ++j4) {
          float4 a = A4[TSW(t, j4)];
          float4 v = v4[j4], pq = p4[j4];
          float qx = pq.x - K * v.x, qy = pq.y - K * v.y;
          float qz = pq.z - K * v.z, qw = pq.w - K * v.w;
          a.x -= vi * qx + qi * v.x;
          a.y -= vi * qy + qi * v.y;
          a.z -= vi * qz + qi * v.z;
          a.w -= vi * qw + qi * v.w;
          A4[TSW(t, j4)] = a;
        }
      }
    }
  }
  __syncthreads();
  if (t == 0) {
    dv[126]  = AEL(126, 126);
    evr[126] = AEL(127, 126);
    dv[127]  = AEL(127, 127);
    evr[127] = 0.0f;
  }
  __syncthreads();
  dvec_g[bb * 128 + t] = dv[t];
  evec_g[bb * 128 + t] = evr[t];
}

// ============================ K8: bisection eigenvalues + normalize ============================
__global__ __launch_bounds__(128) void k_bisect(const float* __restrict__ dvec_g,
                                                const float* __restrict__ evec_g,
                                                float* __restrict__ dist_out) {
  const int bb = blockIdx.x, t = threadIdx.x;
  __shared__ float ds[128], e2s[128], eabs[128];
  __shared__ float rr[2];
  ds[t] = dvec_g[bb * 128 + t];
  float e = evec_g[bb * 128 + t];
  e2s[t] = e * e;
  eabs[t] = fabsf(e);
  __syncthreads();
  float lo = 1e30f, hi = -1e30f;
  for (int ii = 0; ii < 128; ++ii) {
    float r = (ii > 0 ? eabs[ii - 1] : 0.0f) + (ii < 127 ? eabs[ii] : 0.0f);
    lo = fminf(lo, ds[ii] - r);
    hi = fmaxf(hi, ds[ii] + r);
  }
  for (int it = 0; it < 40; ++it) {
    float mid = 0.5f * (lo + hi);
    int cnt = 0;
    float q = ds[0] - mid;
    if (q < 0.0f) cnt++;
    for (int ii = 1; ii < 128; ++ii) {
      float denom = q;
      if (fabsf(denom) < 1e-25f) denom = (denom < 0.0f) ? -1e-25f : 1e-25f;
      q = (ds[ii] - mid) - __fdividef(e2s[ii - 1], denom);
      if (q < 0.0f) cnt++;
    }
    if (cnt <= t) lo = mid; else hi = mid;
  }
  float lam = 0.5f * (lo + hi);
  float evc = fmaxf(lam, 1e-12f);
  float ssum = evc;
  for (int s = 32; s > 0; s >>= 1) ssum += __shfl_xor(ssum, s);
  if ((t & 63) == 0) rr[t >> 6] = ssum;
  __syncthreads();
  float tot = rr[0] + rr[1];
  dist_out[bb * 128 + t] = evc / tot;
}

// ============================ launch ============================
extern "C" void kernel_launch(void* const* d_in, const int* in_sizes, int n_in,
                              void* d_out, int out_size, void* d_ws, size_t ws_size,
                              hipStream_t stream) {
  const float* x      = (const float*)d_in[0];
  const float* L      = (const float*)d_in[1];
  const float* temp_p = (const float*)d_in[2];
  const float* tgt_p  = (const float*)d_in[3];
  const float* step_p = (const float*)d_in[4];
  float* out = (float*)d_out;
  float* ws  = (float*)d_ws;

  float* bases = ws;                    // 2097152
  float* G     = bases + 2097152;       // 16384
  float* w     = G + 16384;             // 16384
  float* s0    = w + 16384;             // 262144
  float* s1    = s0 + 262144;           // 262144
  float* n0    = s1 + 262144;           // 2048
  float* n1    = n0 + 2048;             // 2048
  float* dv    = n1 + 2048;             // 2048
  float* ev    = dv + 2048;             // 2048

  float* o_avg  = out;                  // 2048
  float* o_dist = out + 2048;           // 2048
  float* o_rho  = out + 4096;           // 262144
  float* o_meas = out + 266240;         // 262144
  float* o_eq   = out + 528384;         // 262144
  float* o_expr = out + 790528;         // 262144
  float* o_ten  = out + 1052672;        // 16384

  hipFuncSetAttribute((const void*)k_cayley,
                      hipFuncAttributeMaxDynamicSharedMemorySize, 65536);
  hipFuncSetAttribute((const void*)k_tridiag,
                      hipFuncAttributeMaxDynamicSharedMemorySize, 68160);

  k_cayley<<<128, 512, 65536, stream>>>(L, bases);
  k_gram<<<128, 256, 0, stream>>>(bases, G);
  k_wsoft<<<128, 128, 0, stream>>>(G, temp_p, w, o_ten);
  k_meas<<<128, 128, 0, stream>>>(x, bases, o_meas, s0, n0);
  k_step<<<2048, 128, 0, stream>>>(s0, s1, w, n0, n1, tgt_p, step_p);
  k_step<<<2048, 128, 0, stream>>>(s1, s0, w, n1, n0, tgt_p, step_p);
  k_step<<<2048, 128, 0, stream>>>(s0, s1, w, n0, n1, tgt_p, step_p);
  k_step<<<2048, 128, 0, stream>>>(s1, s0, w, n1, n0, tgt_p, step_p);
  k_step<<<2048, 128, 0, stream>>>(s0, o_eq, w, n0, n1, tgt_p, step_p);
  k_expr<<<128, 128, 0, stream>>>(o_eq, bases, o_expr);
  k_avg<<<16, 128, 0, stream>>>(o_expr, o_avg);
  k_rho<<<128, 256, 0, stream>>>(o_eq, n1, o_rho);
  k_tridiag<<<16, 128, 68160, stream>>>(o_rho, dv, ev);
  k_bisect<<<16, 128, 0, stream>>>(dv, ev, o_dist);
}

// Round 6
// 1358.789 us; speedup vs baseline: 1.6806x; 1.3600x over previous
//
#include <hip/hip_runtime.h>

// Problem constants: BATCH=16, N=128, D=128, N_STEPS=5, EPS=1e-10
#define EPSF 1e-10f

// ============================ K1: Cayley bases ============================
// M = I + A, A = L - L^T. Symmetric part of M is I (SPD) => unpivoted
// Gauss-Jordan is stable (all pivots >= 1). U = 2*M^{-1} - I.
// LDS layout: float4 (i, j4) stored at f4 index i*32 + (j4 ^ (i & 31)).
// Lane map: row i = wave*16 + (lane&15), chunk h = lane>>4 (4 threads/row,
// 8 float4 each). Each 8-lane beat hits 8 distinct rows -> swizzled
// addresses span all 8 bank groups -> conflict-free b128.
// SCRATCH FIX (r5): `((float*)&v)[k & 3] = x` (runtime component index into
// a register float4) forces an alloca -> scratch store/reload in the inner
// loop + vmcnt(0) drain at each barrier (Rule #20). Replaced by branchless
// per-component selects (compile-time lanes, v_cndmask).
#define SWZ4(i, j4) ((i) * 32 + ((j4) ^ ((i) & 31)))
#define SWZF(i, j) (SWZ4((i), (j) >> 2) * 4 + ((j) & 3))

__global__ __launch_bounds__(512, 2) void k_cayley(const float* __restrict__ L,
                                                   float* __restrict__ bases) {
  extern __shared__ float4 M4[];  // 4096 float4 = 64 KB
  float* Mf = (float*)M4;
  const int n = blockIdx.x, t = threadIdx.x;
  const float* Ln = L + n * 16384;
  // load linear -> swizzled (coalesced global reads)
  for (int f = t; f < 4096; f += 512) {
    int i = f >> 5, j4 = f & 31;
    M4[SWZ4(i, j4)] = ((const float4*)Ln)[f];
  }
  __syncthreads();
  // antisymmetrize in place + unit diagonal (pair (i<j) owned by one thread)
  for (int f = t; f < 16384; f += 512) {
    int i = f >> 7, j = f & 127;
    if (i < j) {
      int a = SWZF(i, j), b = SWZF(j, i);
      float va = Mf[a], vb = Mf[b];
      Mf[a] = va - vb;
      Mf[b] = vb - va;
    } else if (i == j) {
      Mf[SWZF(i, i)] = 1.0f;
    }
  }
  __syncthreads();
  const int lane = t & 63, wva = t >> 6;
  const int i = wva * 16 + (lane & 15);  // row owned by this thread
  const int h = lane >> 4;               // which 8-float4 chunk of the row
  for (int k = 0; k < 128; ++k) {
    // ---- phase A: cross-thread reads only (pivot, multiplier, row k)
    float pivinv = 1.0f / Mf[SWZF(k, k)];   // broadcast
    float m = Mf[SWZF(i, k)];               // column read, conflict-spread
    float4 rk[8];
    #pragma unroll
    for (int u = 0; u < 8; ++u) rk[u] = M4[SWZ4(k, h * 8 + u)];  // bcast/beat
    __syncthreads();
    // ---- phase B: stream own row slice (self-owned: no cross-thread race)
    const int kj4 = k >> 2;  // float4 index of pivot column
    const int kc  = k & 3;   // component within it
    float coef = m * pivinv;
    if (i == k) {
      #pragma unroll
      for (int u = 0; u < 8; ++u) {
        int jj = h * 8 + u;
        float4 v = rk[u];
        v.x *= pivinv; v.y *= pivinv; v.z *= pivinv; v.w *= pivinv;
        if (jj == kj4) {  // branchless component patch (no dynamic indexing)
          v.x = (kc == 0) ? pivinv : v.x;
          v.y = (kc == 1) ? pivinv : v.y;
          v.z = (kc == 2) ? pivinv : v.z;
          v.w = (kc == 3) ? pivinv : v.w;
        }
        M4[SWZ4(k, jj)] = v;
      }
    } else {
      #pragma unroll
      for (int u = 0; u < 8; ++u) {
        int jj = h * 8 + u;
        float4 av = M4[SWZ4(i, jj)];  // streamed, not preloaded (no spill)
        float4 r = rk[u];
        av.x -= coef * r.x; av.y -= coef * r.y;
        av.z -= coef * r.z; av.w -= coef * r.w;
        if (jj == kj4) {  // branchless component patch (no dynamic indexing)
          av.x = (kc == 0) ? -coef : av.x;
          av.y = (kc == 1) ? -coef : av.y;
          av.z = (kc == 2) ? -coef : av.z;
          av.w = (kc == 3) ? -coef : av.w;
        }
        M4[SWZ4(i, jj)] = av;
      }
    }
    __syncthreads();
  }
  // write U = 2*Minv - I (coalesced global writes)
  for (int f = t; f < 16384; f += 512) {
    int ii = f >> 7, j = f & 127;
    float v = Mf[SWZF(ii, j)];
    bases[n * 16384 + f] = 2.0f * v - ((ii == j) ? 1.0f : 0.0f);
  }
}

// ============================ K2a: Gram of flattened bases ============================
__global__ __launch_bounds__(256) void k_gram(const float* __restrict__ bases,
                                              float* __restrict__ G) {
  const int i = blockIdx.x, t = threadIdx.x;
  __shared__ float redb[4];
  float4 ai[16];
  const float4* Bi = (const float4*)(bases + i * 16384);
  #pragma unroll
  for (int u = 0; u < 16; ++u) ai[u] = Bi[t + 256 * u];
  for (int j = 0; j < 128; ++j) {
    const float4* Bj = (const float4*)(bases + j * 16384);
    float acc = 0.f;
    #pragma unroll
    for (int u = 0; u < 16; ++u) {
      float4 b = Bj[t + 256 * u];
      acc += ai[u].x * b.x + ai[u].y * b.y + ai[u].z * b.z + ai[u].w * b.w;
    }
    for (int s = 32; s > 0; s >>= 1) acc += __shfl_down(acc, s);
    if ((t & 63) == 0) redb[t >> 6] = acc;
    __syncthreads();
    if (t == 0) G[i * 128 + j] = redb[0] + redb[1] + redb[2] + redb[3];
    __syncthreads();
  }
}

// ============================ K2b: tension + softmax + mask ============================
__global__ __launch_bounds__(128) void k_wsoft(const float* __restrict__ G,
                                               const float* __restrict__ temp_p,
                                               float* __restrict__ w,
                                               float* __restrict__ tension_out) {
  const int i = blockIdx.x, t = threadIdx.x;  // t = j
  __shared__ float rr[2], r2[2];
  float temp = fmaxf(fabsf(*temp_p), 0.01f);
  float gii = G[i * 128 + i], gjj = G[t * 128 + t], gij = G[i * 128 + t];
  float ten = sqrtf(fmaxf(gii + gjj - 2.0f * gij, 0.0f) + 1e-8f);
  tension_out[i * 128 + t] = ten;
  float logit = -ten / temp;
  float m = logit;
  for (int s = 32; s > 0; s >>= 1) m = fmaxf(m, __shfl_xor(m, s));
  if ((t & 63) == 0) rr[t >> 6] = m;
  __syncthreads();
  float mx = fmaxf(rr[0], rr[1]);
  float ex = expf(logit - mx);
  float ssum = ex;
  for (int s = 32; s > 0; s >>= 1) ssum += __shfl_xor(ssum, s);
  if ((t & 63) == 0) r2[t >> 6] = ssum;
  __syncthreads();
  float tot = r2[0] + r2[1];
  float wv = ex / tot;
  if (t == i) wv = 0.0f;
  w[i * 128 + t] = wv;
}

// ============================ K3: measurements + initial norms ============================
__global__ __launch_bounds__(128) void k_meas(const float* __restrict__ x,
                                              const float* __restrict__ bases,
                                              float* __restrict__ meas_out,
                                              float* __restrict__ state0,
                                              float* __restrict__ norms0) {
  const int n = blockIdx.x, t = threadIdx.x;  // t = k
  __shared__ float xs[2048];
  __shared__ float red[2];
  for (int f = t; f < 2048; f += 128) xs[f] = x[f];
  __syncthreads();
  float acc[16];
  #pragma unroll
  for (int b = 0; b < 16; ++b) acc[b] = 0.f;
  for (int d = 0; d < 128; ++d) {
    float u = bases[n * 16384 + d * 128 + t];  // coalesced over t
    #pragma unroll
    for (int b = 0; b < 16; ++b) acc[b] += xs[b * 128 + d] * u;
  }
  for (int b = 0; b < 16; ++b) {
    meas_out[(b * 128 + n) * 128 + t] = acc[b];
    state0[(b * 128 + n) * 128 + t] = acc[b];
  }
  for (int b = 0; b < 16; ++b) {
    float v = acc[b] * acc[b];
    for (int s = 32; s > 0; s >>= 1) v += __shfl_down(v, s);
    if ((t & 63) == 0) red[t >> 6] = v;
    __syncthreads();
    if (t == 0) norms0[b * 128 + n] = sqrtf(red[0] + red[1]);
    __syncthreads();
  }
}

// ============================ K4: one interaction step ============================
__global__ __launch_bounds__(128) void k_step(const float* __restrict__ src,
                                              float* __restrict__ dst,
                                              const float* __restrict__ w,
                                              const float* __restrict__ norms_in,
                                              float* __restrict__ norms_out,
                                              const float* __restrict__ tgt_p,
                                              const float* __restrict__ step_p) {
  const int b = blockIdx.x >> 7, n = blockIdx.x & 127, t = threadIdx.x;
  __shared__ float sn[128];
  __shared__ float chunk[32][129];
  __shared__ float red[2][32][2];
  __shared__ float cbuf[32];
  __shared__ float red2[2];
  const float target = *tgt_p;
  const float step = fminf(fmaxf(fabsf(*step_p), 0.001f), 0.5f);
  const float* srcb = src + b * 16384;
  float x_d = srcb[n * 128 + t];
  sn[t] = x_d;
  float norm_n = norms_in[b * 128 + n];
  float f_d = 0.0f;
  __syncthreads();
  for (int c0 = 0; c0 < 128; c0 += 32) {
    for (int f = t; f < 4096; f += 128) {
      int row = f >> 7, col = f & 127;
      chunk[row][col] = srcb[(c0 + row) * 128 + col];
    }
    __syncthreads();
    int m = t & 31, q = t >> 5;
    float dp = 0.f, sp = 0.f;
    const float* cr = &chunk[m][0];
    #pragma unroll
    for (int i2 = 0; i2 < 32; ++i2) {
      int dd = q * 32 + i2;
      float smv = cr[dd];
      float snd = sn[dd];
      dp += smv * snd;
      float df = snd - smv;
      sp += df * df;
    }
    dp += __shfl_xor(dp, 32);
    sp += __shfl_xor(sp, 32);
    int wave = t >> 6;
    if ((t & 63) < 32) { red[wave][m][0] = dp; red[wave][m][1] = sp; }
    __syncthreads();
    if (t < 32) {
      float dot = red[0][t][0] + red[1][t][0];
      float sq  = red[0][t][1] + red[1][t][1];
      int mm = c0 + t;
      float norm_m = norms_in[b * 128 + mm];
      float wnm = w[n * 128 + mm];
      float cs = dot / ((norm_n + EPSF) * (norm_m + EPSF));
      float fm = (cs - target) * wnm;
      cbuf[t] = fm / (sqrtf(fmaxf(sq, 0.0f)) + EPSF);
    }
    __syncthreads();
    #pragma unroll
    for (int mi = 0; mi < 32; ++mi) f_d += cbuf[mi] * (x_d - chunk[mi][t]);
    __syncthreads();
  }
  float nv = x_d + step * f_d;
  dst[(b * 128 + n) * 128 + t] = nv;
  float v = nv * nv;
  for (int s = 32; s > 0; s >>= 1) v += __shfl_down(v, s);
  if ((t & 63) == 0) red2[t >> 6] = v;
  __syncthreads();
  if (t == 0) norms_out[b * 128 + n] = sqrtf(red2[0] + red2[1]);
}

// ============================ K5: expressions ============================
__global__ __launch_bounds__(128) void k_expr(const float* __restrict__ eq,
                                              const float* __restrict__ bases,
                                              float* __restrict__ expr_out) {
  const int n = blockIdx.x, t = threadIdx.x;  // t = k
  __shared__ __align__(16) float es[16][128];
  for (int f = t; f < 2048; f += 128)
    es[f >> 7][f & 127] = eq[((f >> 7) * 128 + n) * 128 + (f & 127)];
  __syncthreads();
  float acc[16];
  #pragma unroll
  for (int b = 0; b < 16; ++b) acc[b] = 0.f;
  const float4* U = (const float4*)(bases + n * 16384 + t * 128);
  for (int d4 = 0; d4 < 32; ++d4) {
    float4 u = U[d4];
    #pragma unroll
    for (int b = 0; b < 16; ++b) {
      float4 e4 = ((const float4*)&es[b][0])[d4];
      acc[b] += u.x * e4.x + u.y * e4.y + u.z * e4.z + u.w * e4.w;
    }
  }
  for (int b = 0; b < 16; ++b) expr_out[(b * 128 + n) * 128 + t] = acc[b];
}

// ============================ K5b: output_avg ============================
__global__ __launch_bounds__(128) void k_avg(const float* __restrict__ expr,
                                             float* __restrict__ avg) {
  const int b = blockIdx.x, t = threadIdx.x;
  float s = 0.f;
  for (int n = 0; n < 128; ++n) s += expr[(b * 128 + n) * 128 + t];
  avg[b * 128 + t] = s * (1.0f / 128.0f);
}

// ============================ K6: rho ============================
__global__ __launch_bounds__(256) void k_rho(const float* __restrict__ eq,
                                             const float* __restrict__ norms,
                                             float* __restrict__ rho) {
  const int b = blockIdx.x >> 3, dt = blockIdx.x & 7;
  const int t = threadIdx.x;
  __shared__ float ch[32][129];
  int e = t & 127, dl = t >> 7;
  float acc[8];
  #pragma unroll
  for (int o = 0; o < 8; ++o) acc[o] = 0.f;
  for (int c0 = 0; c0 < 128; c0 += 32) {
    for (int f = t; f < 4096; f += 256) {
      int row = f >> 7, col = f & 127;
      int nn = c0 + row;
      float inv = 1.0f / (norms[b * 128 + nn] + EPSF);
      ch[row][col] = eq[(b * 128 + nn) * 128 + col] * inv;
    }
    __syncthreads();
    for (int nn = 0; nn < 32; ++nn) {
      float me = ch[nn][e];
      #pragma unroll
      for (int o = 0; o < 8; ++o) {
        int d = dt * 16 + dl + o * 2;
        acc[o] += ch[nn][d] * me;
      }
    }
    __syncthreads();
  }
  for (int o = 0; o < 8; ++o) {
    int d = dt * 16 + dl + o * 2;
    rho[(b * 128 + d) * 128 + e] = acc[o] * (1.0f / 128.0f);
  }
}

// ============================ K7: Householder tridiagonalization ============================
// 128 threads (2 waves), float4-swizzled LDS (all b128 traffic), 3 barriers
// per step. v stored dense with zeros below k+1; q = p - K*v folded into the
// rank-2 update (no qv pass). Column read after update is same-thread only,
// so the loop carries no extra barrier. vv ping-pongs by step parity; x0 is
// broadcast via a dedicated slot to avoid the vv[k+1] read/write race.
#define TSW(i, j4) ((i) * 32 + ((j4) ^ ((i) & 31)))
#define AEL(i, j) (Af[TSW((i), (j) >> 2) * 4 + ((j) & 3)])

__global__ __launch_bounds__(128) void k_tridiag(const float* __restrict__ rho,
                                                 float* __restrict__ dvec_g,
                                                 float* __restrict__ evec_g) {
  extern __shared__ float sm[];
  float4* A4  = (float4*)sm;        // 4096 float4 = 64 KB
  float*  Af  = sm;
  float* vvb  = sm + 16384;         // 2 x 128 ping-pong
  float* pv   = vvb + 256;          // 128
  float* dv   = pv + 128;           // 128
  float* evr  = dv + 128;           // 128
  float* redS = evr + 128;          // 2
  float* redK = redS + 2;           // 2
  float* redX = redK + 2;           // 1 (+pad)
  const int bb = blockIdx.x, t = threadIdx.x;
  const int wv = t >> 6;
  const float* R = rho + bb * 16384;
  for (int f = t; f < 4096; f += 128)
    A4[TSW(f >> 5, f & 31)] = ((const float4*)R)[f];
  __syncthreads();
  for (int k = 0; k < 126; ++k) {
    float* vvC = vvb + ((k & 1) << 7);
    // ---- P1: column k -> vv (zeros at t<=k), sigma^2 partials, x0 broadcast
    float c = AEL(t, k);
    vvC[t] = (t > k) ? c : 0.0f;
    if (t == k) dv[k] = c;
    if (t == k + 1) redX[0] = c;
    float s2 = (t > k) ? c * c : 0.0f;
    for (int s = 32; s > 0; s >>= 1) s2 += __shfl_down(s2, s);
    if ((t & 63) == 0) redS[wv] = s2;
    __syncthreads();  // B1
    // ---- P2: alpha/beta redundant per-thread; patch vv[k+1]
    float sig2 = redS[0] + redS[1];
    float x0 = redX[0];
    bool skip = (sig2 < 1e-30f);
    float sig = sqrtf(sig2);
    float alpha = (x0 >= 0.0f) ? -sig : sig;
    float beta = skip ? 0.0f : 1.0f / (sig2 - alpha * x0);
    float w0 = x0 - alpha;
    if (t == k + 1) {
      evr[k] = skip ? 0.0f : alpha;
      if (!skip) vvC[t] = w0;
    }
    __syncthreads();  // B2
    if (!skip) {  // uniform branch
      const int j4min = (k + 1) >> 2;
      // ---- P3: matvec p = beta * A v (row per thread), K partials
      float pp = 0.0f;
      if (t > k) {
        const float4* v4 = (const float4*)vvC;
        for (int j4 = j4min; j4 < 32; ++j4) {
          float4 a = A4[TSW(t, j4)];
          float4 v = v4[j4];
          pp += a.x * v.x + a.y * v.y + a.z * v.z + a.w * v.w;
        }
      }
      float p = beta * pp;
      pv[t] = p;                 // zero for t<=k
      float kp = vvC[t] * p;     // zero for t<=k
      for (int s = 32; s > 0; s >>= 1) kp += __shfl_down(kp, s);
      if ((t & 63) == 0) redK[wv] = kp;
      __syncthreads();  // B3
      // ---- P4: rank-2 update A -= v q^T + q v^T, q = p - K v on the fly
      float K = (redK[0] + redK[1]) * beta * 0.5f;
      if (t > k) {
        float vi = vvC[t];
        float qi = pv[t] - K * vi;
        const float4* v4 = (const float4*)vvC;
        const float4* p4 = (const float4*)pv;
        for (int j4 = j4min; j4 < 32; ++j4) {
          float4 a = A4[TSW(t, j4)];
          float4 v = v4[j4], pq = p4[j4];
          float qx = pq.x - K * v.x, qy = pq.y - K * v.y;
          float qz = pq.z - K * v.z, qw = pq.w - K * v.w;
          a.x -= vi * qx + qi * v.x;
          a.y -= vi * qy + qi * v.y;
          a.z -= vi * qz + qi * v.z;
          a.w -= vi * qw + qi * v.w;
          A4[TSW(t, j4)] = a;
        }
      }
    }
  }
  __syncthreads();
  if (t == 0) {
    dv[126]  = AEL(126, 126);
    evr[126] = AEL(127, 126);
    dv[127]  = AEL(127, 127);
    evr[127] = 0.0f;
  }
  __syncthreads();
  dvec_g[bb * 128 + t] = dv[t];
  evec_g[bb * 128 + t] = evr[t];
}

// ============================ K8: bisection eigenvalues + normalize ============================
__global__ __launch_bounds__(128) void k_bisect(const float* __restrict__ dvec_g,
                                                const float* __restrict__ evec_g,
                                                float* __restrict__ dist_out) {
  const int bb = blockIdx.x, t = threadIdx.x;
  __shared__ float ds[128], e2s[128], eabs[128];
  __shared__ float rr[2];
  ds[t] = dvec_g[bb * 128 + t];
  float e = evec_g[bb * 128 + t];
  e2s[t] = e * e;
  eabs[t] = fabsf(e);
  __syncthreads();
  float lo = 1e30f, hi = -1e30f;
  for (int ii = 0; ii < 128; ++ii) {
    float r = (ii > 0 ? eabs[ii - 1] : 0.0f) + (ii < 127 ? eabs[ii] : 0.0f);
    lo = fminf(lo, ds[ii] - r);
    hi = fmaxf(hi, ds[ii] + r);
  }
  for (int it = 0; it < 40; ++it) {
    float mid = 0.5f * (lo + hi);
    int cnt = 0;
    float q = ds[0] - mid;
    if (q < 0.0f) cnt++;
    for (int ii = 1; ii < 128; ++ii) {
      float denom = q;
      if (fabsf(denom) < 1e-25f) denom = (denom < 0.0f) ? -1e-25f : 1e-25f;
      q = (ds[ii] - mid) - __fdividef(e2s[ii - 1], denom);
      if (q < 0.0f) cnt++;
    }
    if (cnt <= t) lo = mid; else hi = mid;
  }
  float lam = 0.5f * (lo + hi);
  float evc = fmaxf(lam, 1e-12f);
  float ssum = evc;
  for (int s = 32; s > 0; s >>= 1) ssum += __shfl_xor(ssum, s);
  if ((t & 63) == 0) rr[t >> 6] = ssum;
  __syncthreads();
  float tot = rr[0] + rr[1];
  dist_out[bb * 128 + t] = evc / tot;
}

// ============================ launch ============================
extern "C" void kernel_launch(void* const* d_in, const int* in_sizes, int n_in,
                              void* d_out, int out_size, void* d_ws, size_t ws_size,
                              hipStream_t stream) {
  const float* x      = (const float*)d_in[0];
  const float* L      = (const float*)d_in[1];
  const float* temp_p = (const float*)d_in[2];
  const float* tgt_p  = (const float*)d_in[3];
  const float* step_p = (const float*)d_in[4];
  float* out = (float*)d_out;
  float* ws  = (float*)d_ws;

  float* bases = ws;                    // 2097152
  float* G     = bases + 2097152;       // 16384
  float* w     = G + 16384;             // 16384
  float* s0    = w + 16384;             // 262144
  float* s1    = s0 + 262144;           // 262144
  float* n0    = s1 + 262144;           // 2048
  float* n1    = n0 + 2048;             // 2048
  float* dv    = n1 + 2048;             // 2048
  float* ev    = dv + 2048;             // 2048

  float* o_avg  = out;                  // 2048
  float* o_dist = out + 2048;           // 2048
  float* o_rho  = out + 4096;           // 262144
  float* o_meas = out + 266240;         // 262144
  float* o_eq   = out + 528384;         // 262144
  float* o_expr = out + 790528;         // 262144
  float* o_ten  = out + 1052672;        // 16384

  hipFuncSetAttribute((const void*)k_cayley,
                      hipFuncAttributeMaxDynamicSharedMemorySize, 65536);
  hipFuncSetAttribute((const void*)k_tridiag,
                      hipFuncAttributeMaxDynamicSharedMemorySize, 68160);

  k_cayley<<<128, 512, 65536, stream>>>(L, bases);
  k_gram<<<128, 256, 0, stream>>>(bases, G);
  k_wsoft<<<128, 128, 0, stream>>>(G, temp_p, w, o_ten);
  k_meas<<<128, 128, 0, stream>>>(x, bases, o_meas, s0, n0);
  k_step<<<2048, 128, 0, stream>>>(s0, s1, w, n0, n1, tgt_p, step_p);
  k_step<<<2048, 128, 0, stream>>>(s1, s0, w, n1, n0, tgt_p, step_p);
  k_step<<<2048, 128, 0, stream>>>(s0, s1, w, n0, n1, tgt_p, step_p);
  k_step<<<2048, 128, 0, stream>>>(s1, s0, w, n1, n0, tgt_p, step_p);
  k_step<<<2048, 128, 0, stream>>>(s0, o_eq, w, n0, n1, tgt_p, step_p);
  k_expr<<<128, 128, 0, stream>>>(o_eq, bases, o_expr);
  k_avg<<<16, 128, 0, stream>>>(o_expr, o_avg);
  k_rho<<<128, 256, 0, stream>>>(o_eq, n1, o_rho);
  k_tridiag<<<16, 128, 68160, stream>>>(o_rho, dv, ev);
  k_bisect<<<16, 128, 0, stream>>>(dv, ev, o_dist);
}